// Round 10
// baseline (513.580 us; speedup 1.0000x reference)
//
#include <hip/hip_runtime.h>
#include <hip/hip_bf16.h>
#include <stdint.h>

#define E_   16
#define T_   512
#define KTOP 8
#define H_   2048
#define I_   1024
#define TK_  4096

typedef __attribute__((ext_vector_type(4))) int i32x4;

// ---- ws layout (bytes) ----
#define OFF_CNT     0                          // u32[16]
#define OFF_ROWMAX  4096                       // u32[4096]
#define OFF_XQ      32768                      // i8 [512][2048] = 1MB
#define OFF_S0      (OFF_XQ + T_*H_)           // f32[512]
#define OFF_S1      (OFF_S0 + 4096)            // f32[4096]
#define OFF_LIST    (OFF_S1 + TK_*4)           // i32[16][4096]
#define OFF_ACT     (OFF_LIST + E_*TK_*4)      // f32[4096][1024] = 16MB
#define OFF_AQ      (OFF_ACT + (size_t)TK_*I_*4)  // i8[4096][1024] = 4MB
#define OFF_Y2      (OFF_AQ + (size_t)TK_*I_)     // bf16[4096][2048] = 16MB

// raw barrier: lgkmcnt(0) for LDS visibility ONLY — VMEM loads stay in flight.
// (__syncthreads would emit vmcnt(0) and destroy the prefetch window.)
#define LBAR() do {                                             \
    asm volatile("s_waitcnt lgkmcnt(0)" ::: "memory");          \
    __builtin_amdgcn_s_barrier();                               \
  } while (0)

// ---------------- zero counts + rowmax ----------------
__global__ void k_zero(unsigned int* __restrict__ p) {
  int i = blockIdx.x * 256 + threadIdx.x;
  if (i < 5120) p[i] = 0;
}

// ---------------- dynamic quant of x -> int8 (+ fused scatter) ----------------
__global__ void k_quant(const float* __restrict__ x, signed char* __restrict__ xq,
                        float* __restrict__ s0, const int* __restrict__ eids,
                        unsigned int* __restrict__ counts, int* __restrict__ row_list) {
  int t = blockIdx.x, tid = threadIdx.x;
  if (tid < KTOP) {
    int e = eids[t * KTOP + tid];
    int pos = (int)atomicAdd(&counts[e], 1u);
    row_list[e * TK_ + pos] = t * KTOP + tid;
  }
  const float4* xr = (const float4*)(x + (size_t)t * H_);
  float4 a = xr[tid * 2 + 0], b = xr[tid * 2 + 1];
  float m = fmaxf(
      fmaxf(fmaxf(fabsf(a.x), fabsf(a.y)), fmaxf(fabsf(a.z), fabsf(a.w))),
      fmaxf(fmaxf(fabsf(b.x), fabsf(b.y)), fmaxf(fabsf(b.z), fabsf(b.w))));
  for (int o = 32; o > 0; o >>= 1) m = fmaxf(m, __shfl_xor(m, o));
  __shared__ float wm[4];
  if ((tid & 63) == 0) wm[tid >> 6] = m;
  __syncthreads();
  m = fmaxf(fmaxf(wm[0], wm[1]), fmaxf(wm[2], wm[3]));
  float s = m / 127.0f;
  if (!(s > 0.f)) s = 1.0f;
  if (tid == 0) s0[t] = s;
  float v[8] = {a.x, a.y, a.z, a.w, b.x, b.y, b.z, b.w};
  unsigned int lo = 0, hi = 0;
#pragma unroll
  for (int j = 0; j < 4; ++j) {
    float qf = fminf(fmaxf(rintf(v[j] / s), -128.f), 127.f);
    lo |= ((unsigned)((int)qf & 0xFF)) << (8 * j);
  }
#pragma unroll
  for (int j = 0; j < 4; ++j) {
    float qf = fminf(fmaxf(rintf(v[4 + j] / s), -128.f), 127.f);
    hi |= ((unsigned)((int)qf & 0xFF)) << (8 * j);
  }
  ((uint2*)(xq + (size_t)t * H_))[tid] = make_uint2(lo, hi);
}

// ---------------- grouped GEMM common ----------------
// 512 thr / 8 waves; BM=384 (8 waves x 48 rows = 3 m-frags); 64 weight cols.
// B: wave w reads k-rows {t*64 + w*8 + j}, lane = dword of the row's contiguous
//    segment (coalesced) -> pack 8 k-bytes of one col -> uint2 -> LDS [n][k] s80.
// A: direct-to-reg dwordx4 (row gather), never touches LDS.
// Pipeline: 1 raw barrier/tile, LDS dbuf, B 3-banked (dist 2), A 2-banked (dist 2).
// Compiler inserts exact counted vmcnt per use; NO vmcnt(0) anywhere in the loop.
#define BM_    384
#define WSTR   2048
#define BSTR   5120   // one LDS B buffer: 64 cols x 80B

#define PACKU2(SRC) (make_uint2(                                          \
    ((SRC)[0] & 0xFF) | (((SRC)[1] & 0xFF) << 8) |                        \
    (((SRC)[2] & 0xFF) << 16) | ((SRC)[3] << 24),                         \
    ((SRC)[4] & 0xFF) | (((SRC)[5] & 0xFF) << 8) |                        \
    (((SRC)[6] & 0xFF) << 16) | ((SRC)[7] << 24)))

#define LOADB(BANK, TT)                                                   \
    _Pragma("unroll")                                                     \
    for (int j_ = 0; j_ < 8; ++j_)                                        \
      BANK[j_] = bsrc[(size_t)((TT) * 64 + brow0 + j_) * WSTR];

#define LOADA(BANK, TT)                                                   \
    _Pragma("unroll")                                                     \
    for (int mi_ = 0; mi_ < 3; ++mi_)                                     \
      BANK[mi_] = *(const i32x4*)(gA[mi_] + (TT) * 64);

#define WRITEB(BANK, BUF)                                                 \
    *(uint2*)(bsm + (BUF) * BSTR + lane * 80 + w * 8) = PACKU2(BANK);

#define MFMAS(BUF, ABANK)                                                 \
    _Pragma("unroll")                                                     \
    for (int f_ = 0; f_ < 4; ++f_) {                                      \
      i32x4 bf_ = *(const i32x4*)(bsm + (BUF) * BSTR +                    \
                                  (f_ * 16 + l15) * 80 + l4 * 16);        \
      _Pragma("unroll")                                                   \
      for (int mi_ = 0; mi_ < 3; ++mi_)                                   \
        acc[mi_][f_] = __builtin_amdgcn_mfma_i32_16x16x64_i8(             \
            ABANK, bf_, acc[mi_][f_], 0, 0, 0);                           \
    }

// Full K-sweep: prologue issues B0,A01 (B tiles 0..2, A tiles 0..1), then one
// barrier per tile.  At iter t: MFMA(t) [waits A(t)], stage B(t+1) [waits
// B(t+1), loaded 2 iters ago], reload A(t+2)/B(t+3).
#define KSWEEP(NT)                                                        \
    LOADB(bB[0], 0); LOADA(aA0, 0);                                       \
    LOADB(bB[1], 1); LOADA(aA1, 1);                                       \
    LOADB(bB[2], 2);                                                      \
    WRITEB(bB[0], 0);                                                     \
    LBAR();                                                               \
    _Pragma("unroll")                                                     \
    for (int t = 0; t < (NT); ++t) {                                      \
      if ((t & 1) == 0) {                                                 \
        MFMAS(0, aA0[mi_]);                                               \
      } else {                                                            \
        MFMAS(1, aA1[mi_]);                                               \
      }                                                                   \
      if (t + 1 < (NT)) { WRITEB(bB[(t + 1) % 3], (t + 1) & 1); }         \
      if (t + 2 < (NT)) {                                                 \
        if ((t & 1) == 0) { LOADA(aA0, t + 2); }                          \
        else              { LOADA(aA1, t + 2); }                          \
      }                                                                   \
      if (t + 3 < (NT)) { LOADB(bB[t % 3], t + 3); }                      \
      LBAR();                                                             \
    }

// ---------------- grouped GEMM1 + SwiGLU + rowmax ----------------
__launch_bounds__(512, 4)
__global__ void k_gemm1(const signed char* __restrict__ xq, const int* __restrict__ w1,
                        const float* __restrict__ ws1, const float* __restrict__ s0,
                        const unsigned int* __restrict__ counts,
                        const int* __restrict__ row_list,
                        float* __restrict__ act, unsigned int* __restrict__ rowmax) {
  __shared__ alignas(16) char bsm[2 * BSTR];
  int e = blockIdx.y;
  int cnt = (int)counts[e];
  if (cnt == 0) return;
  int p0 = blockIdx.x * 32;            // 32 act cols (32 L + 32 R weight cols)
  const int* rl = row_list + e * TK_;
  const int* we = w1 + (size_t)e * H_ * (2 * I_);
  const float* wsc = ws1 + (size_t)e * (2 * I_);

  int tid = threadIdx.x, w = tid >> 6, lane = tid & 63;
  int l15 = lane & 15, l4 = lane >> 4;

  int bcol = (lane < 32) ? (p0 + lane) : (I_ + p0 + (lane - 32));
  const int* bsrc = we + bcol;
  const int brow0 = w * 8;

  const int NT = H_ / 64;   // 32
  for (int ch = 0; ch * BM_ < cnt; ++ch) {
    int rbase = ch * BM_;
    const signed char* gA[3];
#pragma unroll
    for (int mi = 0; mi < 3; ++mi) {
      int gr = rbase + w * 48 + mi * 16 + l15;
      int tok = rl[gr < cnt ? gr : 0] >> 3;
      gA[mi] = xq + (size_t)tok * H_ + l4 * 16;
    }
    i32x4 acc[3][4];
#pragma unroll
    for (int i = 0; i < 3; ++i)
#pragma unroll
      for (int n = 0; n < 4; ++n) acc[i][n] = (i32x4)(0);

    int bB[3][8];
    i32x4 aA0[3], aA1[3];
    KSWEEP(NT);

    // epilogue: dequant + SwiGLU (L=acc[.][n], R=acc[.][n+2]) + rowmax
#pragma unroll
    for (int mi = 0; mi < 3; ++mi) {
#pragma unroll
      for (int r = 0; r < 4; ++r) {
        int gr = rbase + w * 48 + mi * 16 + l4 * 4 + r;
        bool valid = gr < cnt;
        int irow = rl[valid ? gr : 0];
        float s0v = s0[irow >> 3];
        float rowm = 0.f, av0 = 0.f, av1 = 0.f;
#pragma unroll
        for (int n = 0; n < 2; ++n) {
          int colL = p0 + n * 16 + l15;
          float yl = (float)acc[mi][n][r] * wsc[colL] * s0v;
          float yr = (float)acc[mi][n + 2][r] * wsc[I_ + colL] * s0v;
          float actv = (yl / (1.f + expf(-yl))) * yr;
          if (n == 0) av0 = actv; else av1 = actv;
          rowm = fmaxf(rowm, fabsf(actv));
        }
        rowm = fmaxf(rowm, __shfl_xor(rowm, 1));
        rowm = fmaxf(rowm, __shfl_xor(rowm, 2));
        rowm = fmaxf(rowm, __shfl_xor(rowm, 4));
        rowm = fmaxf(rowm, __shfl_xor(rowm, 8));
        if (valid) {
          act[(size_t)irow * I_ + p0 + l15] = av0;
          act[(size_t)irow * I_ + p0 + 16 + l15] = av1;
          if (l15 == 0) atomicMax(rowmax + irow, __float_as_uint(rowm));
        }
      }
    }
  }
}

// ---------------- requant act -> int8 + s1 ----------------
__global__ void k_requant(const float* __restrict__ act, const unsigned int* __restrict__ rowmax,
                          signed char* __restrict__ aq, float* __restrict__ s1) {
  int i = blockIdx.x, tid = threadIdx.x;
  float m = __uint_as_float(rowmax[i]);
  float s = (m > 0.f) ? (m / 127.0f) : 1.0f;
  if (tid == 0) s1[i] = s;
  float4 v = ((const float4*)(act + (size_t)i * I_))[tid];
  float vv[4] = {v.x, v.y, v.z, v.w};
  unsigned int pk = 0;
#pragma unroll
  for (int j = 0; j < 4; ++j) {
    float qf = fminf(fmaxf(rintf(vv[j] / s), -128.f), 127.f);
    pk |= ((unsigned)((int)qf & 0xFF)) << (8 * j);
  }
  ((unsigned int*)(aq + (size_t)i * I_))[tid] = pk;
}

// ---------------- grouped GEMM2 + dequant + es fold -> bf16 ----------------
__launch_bounds__(512, 4)
__global__ void k_gemm2(const signed char* __restrict__ aq, const int* __restrict__ w2,
                        const float* __restrict__ ws2, const float* __restrict__ s1,
                        const float* __restrict__ es,
                        const unsigned int* __restrict__ counts,
                        const int* __restrict__ row_list,
                        __hip_bfloat16* __restrict__ y2h) {
  __shared__ alignas(16) char bsm[2 * BSTR];
  int e = blockIdx.y;
  int cnt = (int)counts[e];
  if (cnt == 0) return;
  int n0 = blockIdx.x * 64;            // 64 cols (256B contiguous per k-row)
  const int* rl = row_list + e * TK_;
  const int* we = w2 + (size_t)e * I_ * H_;
  const float* wsc = ws2 + (size_t)e * H_;

  int tid = threadIdx.x, w = tid >> 6, lane = tid & 63;
  int l15 = lane & 15, l4 = lane >> 4;

  const int* bsrc = we + n0 + lane;
  const int brow0 = w * 8;

  const int NT = I_ / 64;   // 16
  for (int ch = 0; ch * BM_ < cnt; ++ch) {
    int rbase = ch * BM_;
    const signed char* gA[3];
#pragma unroll
    for (int mi = 0; mi < 3; ++mi) {
      int gr = rbase + w * 48 + mi * 16 + l15;
      gA[mi] = aq + (size_t)rl[gr < cnt ? gr : 0] * I_ + l4 * 16;
    }
    i32x4 acc[3][4];
#pragma unroll
    for (int i = 0; i < 3; ++i)
#pragma unroll
      for (int n = 0; n < 4; ++n) acc[i][n] = (i32x4)(0);

    int bB[3][8];
    i32x4 aA0[3], aA1[3];
    KSWEEP(NT);

#pragma unroll
    for (int mi = 0; mi < 3; ++mi) {
#pragma unroll
      for (int r = 0; r < 4; ++r) {
        int gr = rbase + w * 48 + mi * 16 + l4 * 4 + r;
        if (gr < cnt) {
          int irow = rl[gr];
          float sc = s1[irow] * es[irow];
#pragma unroll
          for (int n = 0; n < 4; ++n) {
            int c = n0 + n * 16 + l15;
            float v = (float)acc[mi][n][r] * wsc[c] * sc;
            y2h[(size_t)irow * H_ + c] = __float2bfloat16(v);
          }
        }
      }
    }
  }
}

// ---------------- combine (es already folded) ----------------
__global__ void k_combine(const __hip_bfloat16* __restrict__ y2h, float* __restrict__ out) {
  int idx = blockIdx.x * 256 + threadIdx.x;
  int t = idx >> 8;
  int h0 = (idx & 255) * 8;
  float s[8];
#pragma unroll
  for (int j = 0; j < 8; ++j) s[j] = 0.f;
#pragma unroll
  for (int k = 0; k < KTOP; ++k) {
    const __hip_bfloat16* p = y2h + ((size_t)(t * KTOP + k) * H_ + h0);
    uint4 u = *(const uint4*)p;
    const __hip_bfloat16* b = (const __hip_bfloat16*)&u;
#pragma unroll
    for (int j = 0; j < 8; ++j) s[j] += __bfloat162float(b[j]);
  }
  float4 o0 = make_float4(s[0], s[1], s[2], s[3]);
  float4 o1 = make_float4(s[4], s[5], s[6], s[7]);
  float4* dst = (float4*)(out + (size_t)t * H_ + h0);
  dst[0] = o0; dst[1] = o1;
}

extern "C" void kernel_launch(void* const* d_in, const int* in_sizes, int n_in,
                              void* d_out, int out_size, void* d_ws, size_t ws_size,
                              hipStream_t stream) {
  const float* x   = (const float*)d_in[0];
  const int*   eid = (const int*)d_in[1];
  const int*   w1  = (const int*)d_in[2];
  const float* ws1 = (const float*)d_in[3];
  const int*   w2  = (const int*)d_in[4];
  const float* ws2 = (const float*)d_in[5];
  const float* es  = (const float*)d_in[7];
  float* out = (float*)d_out;
  char* ws = (char*)d_ws;

  unsigned int*  counts   = (unsigned int*)(ws + OFF_CNT);
  unsigned int*  rowmax   = (unsigned int*)(ws + OFF_ROWMAX);
  signed char*   xq       = (signed char*)(ws + OFF_XQ);
  float*         s0       = (float*)(ws + OFF_S0);
  float*         s1       = (float*)(ws + OFF_S1);
  int*           row_list = (int*)(ws + OFF_LIST);
  float*         act      = (float*)(ws + OFF_ACT);
  signed char*   aq       = (signed char*)(ws + OFF_AQ);
  __hip_bfloat16* y2h     = (__hip_bfloat16*)(ws + OFF_Y2);

  k_zero<<<20, 256, 0, stream>>>((unsigned int*)ws);
  k_quant<<<T_, 256, 0, stream>>>(x, xq, s0, eid, counts, row_list);
  k_gemm1<<<dim3(32, E_), 512, 0, stream>>>(xq, w1, ws1, s0, counts, row_list, act, rowmax);
  k_requant<<<TK_, 256, 0, stream>>>(act, rowmax, aq, s1);
  k_gemm2<<<dim3(32, E_), 512, 0, stream>>>(aq, w2, ws2, s1, es, counts, row_list, y2h);
  k_combine<<<(T_ * H_ / 8) / 256, 256, 0, stream>>>(y2h, out);
}

// Round 11
// 184.113 us; speedup vs baseline: 2.7895x; 2.7895x over previous
//
#include <hip/hip_runtime.h>
#include <hip/hip_bf16.h>
#include <stdint.h>

#define E_   16
#define T_   512
#define KTOP 8
#define H_   2048
#define I_   1024
#define TK_  4096

typedef __attribute__((ext_vector_type(4))) int i32x4;

// ---- ws layout (bytes) ----
#define OFF_CNT     0                          // u32[16]
#define OFF_ROWMAX  4096                       // u32[4096]
#define OFF_XQ      32768                      // i8 [512][2048] = 1MB
#define OFF_S0      (OFF_XQ + T_*H_)           // f32[512]
#define OFF_S1      (OFF_S0 + 4096)            // f32[4096]
#define OFF_LIST    (OFF_S1 + TK_*4)           // i32[16][4096]
#define OFF_ACT     (OFF_LIST + E_*TK_*4)      // f32[4096][1024] = 16MB
#define OFF_AQ      (OFF_ACT + (size_t)TK_*I_*4)  // i8[4096][1024] = 4MB
#define OFF_Y2      (OFF_AQ + (size_t)TK_*I_)     // bf16[4096][2048] = 16MB

// raw barrier: lgkmcnt(0) for LDS visibility ONLY — register VMEM loads stay in
// flight across it (compiler inserts exact counted vmcnt at each register use).
#define LBAR() do {                                             \
    asm volatile("s_waitcnt lgkmcnt(0)" ::: "memory");          \
    __builtin_amdgcn_s_barrier();                               \
  } while (0)

// ---------------- zero counts + rowmax ----------------
__global__ void k_zero(unsigned int* __restrict__ p) {
  int i = blockIdx.x * 256 + threadIdx.x;
  if (i < 5120) p[i] = 0;
}

// ---------------- dynamic quant of x -> int8 (+ fused scatter) ----------------
__global__ void k_quant(const float* __restrict__ x, signed char* __restrict__ xq,
                        float* __restrict__ s0, const int* __restrict__ eids,
                        unsigned int* __restrict__ counts, int* __restrict__ row_list) {
  int t = blockIdx.x, tid = threadIdx.x;
  if (tid < KTOP) {
    int e = eids[t * KTOP + tid];
    int pos = (int)atomicAdd(&counts[e], 1u);
    row_list[e * TK_ + pos] = t * KTOP + tid;
  }
  const float4* xr = (const float4*)(x + (size_t)t * H_);
  float4 a = xr[tid * 2 + 0], b = xr[tid * 2 + 1];
  float m = fmaxf(
      fmaxf(fmaxf(fabsf(a.x), fabsf(a.y)), fmaxf(fabsf(a.z), fabsf(a.w))),
      fmaxf(fmaxf(fabsf(b.x), fabsf(b.y)), fmaxf(fabsf(b.z), fabsf(b.w))));
  for (int o = 32; o > 0; o >>= 1) m = fmaxf(m, __shfl_xor(m, o));
  __shared__ float wm[4];
  if ((tid & 63) == 0) wm[tid >> 6] = m;
  __syncthreads();
  m = fmaxf(fmaxf(wm[0], wm[1]), fmaxf(wm[2], wm[3]));
  float s = m / 127.0f;
  if (!(s > 0.f)) s = 1.0f;
  if (tid == 0) s0[t] = s;
  float v[8] = {a.x, a.y, a.z, a.w, b.x, b.y, b.z, b.w};
  unsigned int lo = 0, hi = 0;
#pragma unroll
  for (int j = 0; j < 4; ++j) {
    float qf = fminf(fmaxf(rintf(v[j] / s), -128.f), 127.f);
    lo |= ((unsigned)((int)qf & 0xFF)) << (8 * j);
  }
#pragma unroll
  for (int j = 0; j < 4; ++j) {
    float qf = fminf(fmaxf(rintf(v[4 + j] / s), -128.f), 127.f);
    hi |= ((unsigned)((int)qf & 0xFF)) << (8 * j);
  }
  ((uint2*)(xq + (size_t)t * H_))[tid] = make_uint2(lo, hi);
}

// ---------------- grouped GEMM common ----------------
// 512 thr / 8 waves; BM=384 (8 waves x 48 rows = 3 m-frags); 64 weight cols.
// B: wave w reads k-rows {t*64 + w*8 + j}, lane = dword of the row's contiguous
//    256B segment (coalesced) -> pack 8 k-bytes of one col -> ds_write_b64 into
//    LDS [col][k] stride 80 (r9-proven layout).
// A: direct-to-reg dwordx4 row-gather (r5-proven), never touches LDS.
// Pipeline: distance-2, B/A double-banked in regs, LDS B dbuf, ONE lgkm-only
// barrier per tile.  NO manual vmcnt: every load lands in a register, so the
// compiler emits exact counted waits; nothing drains at the barrier.
#define BM_    384
#define WSTR   2048
#define BSTR   5120   // one LDS B buffer: 64 cols x 80B

#define PACKU2(SRC) (make_uint2(                                          \
    ((SRC)[0] & 0xFF) | (((SRC)[1] & 0xFF) << 8) |                        \
    (((SRC)[2] & 0xFF) << 16) | ((SRC)[3] << 24),                         \
    ((SRC)[4] & 0xFF) | (((SRC)[5] & 0xFF) << 8) |                        \
    (((SRC)[6] & 0xFF) << 16) | ((SRC)[7] << 24)))

#define LOADB(BANK, TT)                                                   \
    _Pragma("unroll")                                                     \
    for (int j_ = 0; j_ < 8; ++j_)                                        \
      BANK[j_] = bsrc[(size_t)((TT) * 64 + brow0 + j_) * WSTR];

#define LOADA(BANK, TT)                                                   \
    _Pragma("unroll")                                                     \
    for (int mi_ = 0; mi_ < 3; ++mi_)                                     \
      BANK[mi_] = *(const i32x4*)(gA[mi_] + (TT) * 64);

#define WRITEB(BANK, BUF)                                                 \
    *(uint2*)(bsm + (BUF) * BSTR + lane * 80 + w * 8) = PACKU2(BANK);

#define MFMAS(BUF, ABANK)                                                 \
    _Pragma("unroll")                                                     \
    for (int f_ = 0; f_ < 4; ++f_) {                                      \
      i32x4 bf_ = *(const i32x4*)(bsm + (BUF) * BSTR +                    \
                                  (f_ * 16 + l15) * 80 + l4 * 16);        \
      _Pragma("unroll")                                                   \
      for (int mi_ = 0; mi_ < 3; ++mi_)                                   \
        acc[mi_][f_] = __builtin_amdgcn_mfma_i32_16x16x64_i8(             \
            ABANK[mi_], bf_, acc[mi_][f_], 0, 0, 0);                      \
    }

// Steady state tile t: load B(t+2)/A(t+2) into the bank just freed, MFMA(t),
// pack B(t+1) into the other LDS buffer, lgkm-only barrier.
#define KSWEEP(NT)                                                        \
    LOADB(bB0, 0); LOADA(aA0, 0);                                         \
    LOADB(bB1, 1); LOADA(aA1, 1);                                         \
    WRITEB(bB0, 0);                                                       \
    LBAR();                                                               \
    _Pragma("unroll 2")                                                   \
    for (int t = 0; t < (NT); ++t) {                                      \
      if (t & 1) {                                                        \
        if (t + 2 < (NT)) { LOADB(bB1, t + 2); }                          \
        MFMAS(1, aA1);                                                    \
        if (t + 2 < (NT)) { LOADA(aA1, t + 2); }                          \
        if (t + 1 < (NT)) { WRITEB(bB0, 0); }                             \
      } else {                                                            \
        if (t + 2 < (NT)) { LOADB(bB0, t + 2); }                          \
        MFMAS(0, aA0);                                                    \
        if (t + 2 < (NT)) { LOADA(aA0, t + 2); }                          \
        if (t + 1 < (NT)) { WRITEB(bB1, 1); }                             \
      }                                                                   \
      LBAR();                                                             \
    }

// ---------------- grouped GEMM1 + SwiGLU + rowmax ----------------
__launch_bounds__(512, 2)
__global__ void k_gemm1(const signed char* __restrict__ xq, const int* __restrict__ w1,
                        const float* __restrict__ ws1, const float* __restrict__ s0,
                        const unsigned int* __restrict__ counts,
                        const int* __restrict__ row_list,
                        float* __restrict__ act, unsigned int* __restrict__ rowmax) {
  __shared__ alignas(16) char bsm[2 * BSTR];
  int e = blockIdx.y;
  int cnt = (int)counts[e];
  if (cnt == 0) return;
  int p0 = blockIdx.x * 32;            // 32 act cols (32 L + 32 R weight cols)
  const int* rl = row_list + e * TK_;
  const int* we = w1 + (size_t)e * H_ * (2 * I_);
  const float* wsc = ws1 + (size_t)e * (2 * I_);

  int tid = threadIdx.x, w = tid >> 6, lane = tid & 63;
  int l15 = lane & 15, l4 = lane >> 4;

  int bcol = (lane < 32) ? (p0 + lane) : (I_ + p0 + (lane - 32));
  const int* bsrc = we + bcol;
  const int brow0 = w * 8;

  const int NT = H_ / 64;   // 32
  for (int ch = 0; ch * BM_ < cnt; ++ch) {
    int rbase = ch * BM_;
    const signed char* gA[3];
#pragma unroll
    for (int mi = 0; mi < 3; ++mi) {
      int gr = rbase + w * 48 + mi * 16 + l15;
      int tok = rl[gr < cnt ? gr : 0] >> 3;
      gA[mi] = xq + (size_t)tok * H_ + l4 * 16;
    }
    i32x4 acc[3][4];
#pragma unroll
    for (int i = 0; i < 3; ++i)
#pragma unroll
      for (int n = 0; n < 4; ++n) acc[i][n] = (i32x4)(0);

    int bB0[8], bB1[8];
    i32x4 aA0[3], aA1[3];
    KSWEEP(NT);

    // epilogue: dequant + SwiGLU (L=acc[.][n], R=acc[.][n+2]) + rowmax
#pragma unroll
    for (int mi = 0; mi < 3; ++mi) {
#pragma unroll
      for (int r = 0; r < 4; ++r) {
        int gr = rbase + w * 48 + mi * 16 + l4 * 4 + r;
        bool valid = gr < cnt;
        int irow = rl[valid ? gr : 0];
        float s0v = s0[irow >> 3];
        float rowm = 0.f, av0 = 0.f, av1 = 0.f;
#pragma unroll
        for (int n = 0; n < 2; ++n) {
          int colL = p0 + n * 16 + l15;
          float yl = (float)acc[mi][n][r] * wsc[colL] * s0v;
          float yr = (float)acc[mi][n + 2][r] * wsc[I_ + colL] * s0v;
          float actv = (yl / (1.f + expf(-yl))) * yr;
          if (n == 0) av0 = actv; else av1 = actv;
          rowm = fmaxf(rowm, fabsf(actv));
        }
        rowm = fmaxf(rowm, __shfl_xor(rowm, 1));
        rowm = fmaxf(rowm, __shfl_xor(rowm, 2));
        rowm = fmaxf(rowm, __shfl_xor(rowm, 4));
        rowm = fmaxf(rowm, __shfl_xor(rowm, 8));
        if (valid) {
          act[(size_t)irow * I_ + p0 + l15] = av0;
          act[(size_t)irow * I_ + p0 + 16 + l15] = av1;
          if (l15 == 0) atomicMax(rowmax + irow, __float_as_uint(rowm));
        }
      }
    }
  }
}

// ---------------- requant act -> int8 + s1 ----------------
__global__ void k_requant(const float* __restrict__ act, const unsigned int* __restrict__ rowmax,
                          signed char* __restrict__ aq, float* __restrict__ s1) {
  int i = blockIdx.x, tid = threadIdx.x;
  float m = __uint_as_float(rowmax[i]);
  float s = (m > 0.f) ? (m / 127.0f) : 1.0f;
  if (tid == 0) s1[i] = s;
  float4 v = ((const float4*)(act + (size_t)i * I_))[tid];
  float vv[4] = {v.x, v.y, v.z, v.w};
  unsigned int pk = 0;
#pragma unroll
  for (int j = 0; j < 4; ++j) {
    float qf = fminf(fmaxf(rintf(vv[j] / s), -128.f), 127.f);
    pk |= ((unsigned)((int)qf & 0xFF)) << (8 * j);
  }
  ((unsigned int*)(aq + (size_t)i * I_))[tid] = pk;
}

// ---------------- grouped GEMM2 + dequant + es fold -> bf16 ----------------
__launch_bounds__(512, 2)
__global__ void k_gemm2(const signed char* __restrict__ aq, const int* __restrict__ w2,
                        const float* __restrict__ ws2, const float* __restrict__ s1,
                        const float* __restrict__ es,
                        const unsigned int* __restrict__ counts,
                        const int* __restrict__ row_list,
                        __hip_bfloat16* __restrict__ y2h) {
  __shared__ alignas(16) char bsm[2 * BSTR];
  int e = blockIdx.y;
  int cnt = (int)counts[e];
  if (cnt == 0) return;
  int n0 = blockIdx.x * 64;            // 64 cols (256B contiguous per k-row)
  const int* rl = row_list + e * TK_;
  const int* we = w2 + (size_t)e * I_ * H_;
  const float* wsc = ws2 + (size_t)e * H_;

  int tid = threadIdx.x, w = tid >> 6, lane = tid & 63;
  int l15 = lane & 15, l4 = lane >> 4;

  const int* bsrc = we + n0 + lane;
  const int brow0 = w * 8;

  const int NT = I_ / 64;   // 16
  for (int ch = 0; ch * BM_ < cnt; ++ch) {
    int rbase = ch * BM_;
    const signed char* gA[3];
#pragma unroll
    for (int mi = 0; mi < 3; ++mi) {
      int gr = rbase + w * 48 + mi * 16 + l15;
      gA[mi] = aq + (size_t)rl[gr < cnt ? gr : 0] * I_ + l4 * 16;
    }
    i32x4 acc[3][4];
#pragma unroll
    for (int i = 0; i < 3; ++i)
#pragma unroll
      for (int n = 0; n < 4; ++n) acc[i][n] = (i32x4)(0);

    int bB0[8], bB1[8];
    i32x4 aA0[3], aA1[3];
    KSWEEP(NT);

#pragma unroll
    for (int mi = 0; mi < 3; ++mi) {
#pragma unroll
      for (int r = 0; r < 4; ++r) {
        int gr = rbase + w * 48 + mi * 16 + l4 * 4 + r;
        if (gr < cnt) {
          int irow = rl[gr];
          float sc = s1[irow] * es[irow];
#pragma unroll
          for (int n = 0; n < 4; ++n) {
            int c = n0 + n * 16 + l15;
            float v = (float)acc[mi][n][r] * wsc[c] * sc;
            y2h[(size_t)irow * H_ + c] = __float2bfloat16(v);
          }
        }
      }
    }
  }
}

// ---------------- combine (es already folded) ----------------
__global__ void k_combine(const __hip_bfloat16* __restrict__ y2h, float* __restrict__ out) {
  int idx = blockIdx.x * 256 + threadIdx.x;
  int t = idx >> 8;
  int h0 = (idx & 255) * 8;
  float s[8];
#pragma unroll
  for (int j = 0; j < 8; ++j) s[j] = 0.f;
#pragma unroll
  for (int k = 0; k < KTOP; ++k) {
    const __hip_bfloat16* p = y2h + ((size_t)(t * KTOP + k) * H_ + h0);
    uint4 u = *(const uint4*)p;
    const __hip_bfloat16* b = (const __hip_bfloat16*)&u;
#pragma unroll
    for (int j = 0; j < 8; ++j) s[j] += __bfloat162float(b[j]);
  }
  float4 o0 = make_float4(s[0], s[1], s[2], s[3]);
  float4 o1 = make_float4(s[4], s[5], s[6], s[7]);
  float4* dst = (float4*)(out + (size_t)t * H_ + h0);
  dst[0] = o0; dst[1] = o1;
}

extern "C" void kernel_launch(void* const* d_in, const int* in_sizes, int n_in,
                              void* d_out, int out_size, void* d_ws, size_t ws_size,
                              hipStream_t stream) {
  const float* x   = (const float*)d_in[0];
  const int*   eid = (const int*)d_in[1];
  const int*   w1  = (const int*)d_in[2];
  const float* ws1 = (const float*)d_in[3];
  const int*   w2  = (const int*)d_in[4];
  const float* ws2 = (const float*)d_in[5];
  const float* es  = (const float*)d_in[7];
  float* out = (float*)d_out;
  char* ws = (char*)d_ws;

  unsigned int*  counts   = (unsigned int*)(ws + OFF_CNT);
  unsigned int*  rowmax   = (unsigned int*)(ws + OFF_ROWMAX);
  signed char*   xq       = (signed char*)(ws + OFF_XQ);
  float*         s0       = (float*)(ws + OFF_S0);
  float*         s1       = (float*)(ws + OFF_S1);
  int*           row_list = (int*)(ws + OFF_LIST);
  float*         act      = (float*)(ws + OFF_ACT);
  signed char*   aq       = (signed char*)(ws + OFF_AQ);
  __hip_bfloat16* y2h     = (__hip_bfloat16*)(ws + OFF_Y2);

  k_zero<<<20, 256, 0, stream>>>((unsigned int*)ws);
  k_quant<<<T_, 256, 0, stream>>>(x, xq, s0, eid, counts, row_list);
  k_gemm1<<<dim3(32, E_), 512, 0, stream>>>(xq, w1, ws1, s0, counts, row_list, act, rowmax);
  k_requant<<<TK_, 256, 0, stream>>>(act, rowmax, aq, s1);
  k_gemm2<<<dim3(32, E_), 512, 0, stream>>>(aq, w2, ws2, s1, es, counts, row_list, y2h);
  k_combine<<<(T_ * H_ / 8) / 256, 256, 0, stream>>>(y2h, out);
}